// Round 5
// baseline (1847.370 us; speedup 1.0000x reference)
//
#include <hip/hip_runtime.h>
#include <cstdint>
#include <cstddef>

typedef short short8 __attribute__((ext_vector_type(8)));
typedef float floatx16 __attribute__((ext_vector_type(16)));
typedef unsigned short u16;

__device__ __forceinline__ u16 f2bf(float f) {
    unsigned u = __float_as_uint(f);
    u += 0x7FFFu + ((u >> 16) & 1u);
    return (u16)(u >> 16);
}
__device__ __forceinline__ float bf2f(u16 h) {
    return __uint_as_float(((unsigned)h) << 16);
}

// ---------------------------------------------------------------------------
// Kernel 1: x [4][72][32][32][32] f32 (NCDHW)  ->  xt [4][32][32][32][72] bf16
// ---------------------------------------------------------------------------
__global__ __launch_bounds__(256) void k_transpose_x(const float* __restrict__ x,
                                                     u16* __restrict__ xt) {
    __shared__ float tile[72 * 33];
    const int bx = blockIdx.x;               // ((b*32+d)*32+h)
    const int tid = threadIdx.x;
    const int b = bx >> 10, d = (bx >> 5) & 31, h = bx & 31;
    const float* src = x + (size_t)b * 72 * 32768 + d * 1024 + h * 32;
    for (int e = tid; e < 2304; e += 256) {
        int ci = e >> 5, w = e & 31;
        tile[ci * 33 + w] = src[(size_t)ci * 32768 + w];
    }
    __syncthreads();
    u16* dst = xt + (size_t)bx * 2304;
    for (int e = tid; e < 2304; e += 256) {
        int w = e / 72, ci = e - w * 72;
        dst[e] = f2bf(tile[ci * 33 + w]);
    }
}

// ---------------------------------------------------------------------------
// Kernel 2: W [176][72][5][5][5] f32 -> wt bf16, 32x32x16 B-fragment layout:
//   wt[kd][kh][ks(23)][nb(6)][lane(64)][8]
//   co = nb*32 + (lane&31); k = ks*16 + (lane>>5)*8 + j  (k = kw*72+ci)
//   zero-pad k>=360 and co>=176.
// ---------------------------------------------------------------------------
__global__ __launch_bounds__(256) void k_prep_w(const float* __restrict__ W,
                                                u16* __restrict__ wt) {
    const int gid = blockIdx.x * 256 + threadIdx.x;   // 3450 frags * 64 = 220800
    if (gid >= 220800) return;
    const int frag = gid >> 6, lane = gid & 63;
    const int nb = frag % 6;
    int t = frag / 6;
    const int ks = t % 23;
    t = t / 23;
    const int kh = t % 5, kd = t / 5;
    const int n = lane & 31, q8 = (lane >> 5) * 8;
    const int co = nb * 32 + n;
    u16 v[8] __attribute__((aligned(16)));
    #pragma unroll
    for (int j = 0; j < 8; ++j) {
        int k = ks * 16 + q8 + j;
        u16 r = 0;
        if (k < 360 && co < 176) {
            int kw = k / 72, ci = k - kw * 72;
            r = f2bf(W[((size_t)co * 72 + ci) * 125 + kd * 25 + kh * 5 + kw]);
        }
        v[j] = r;
    }
    *(uint4*)(wt + (size_t)gid * 8) = *(const uint4*)v;
}

// ---------------------------------------------------------------------------
// Kernel 3: implicit-GEMM conv (32x32x16 MFMA) + fused gating.
// Grid 512 = (b:4, d:32, ht:4). WG 256 thr = 4 waves = 2 M-waves x 2 N-waves.
// Wave tile: mB=4 M-blocks (4 h-rows x 32 w) x nB=3 N-blocks (96 co).
// acc = 12 x 16 = 192 AGPRs; A from LDS, B streamed from L2/L1.
// Gate channels (co 144..175, in wn=1's blocks) exchanged via LDS.
// ---------------------------------------------------------------------------
#define LP 2624

__global__ __launch_bounds__(256, 2) void k_conv(const u16* __restrict__ xt,
                                                 const u16* __restrict__ wt,
                                                 const float* __restrict__ scalar_bias,
                                                 const float* __restrict__ gate_bias,
                                                 u16* __restrict__ zt) {
    __shared__ __align__(16) u16 sx[12 * LP];
    const int bx = blockIdx.x;
    const int ht = bx & 3, d = (bx >> 2) & 31, b = bx >> 7;
    const int h0 = ht * 8;
    const int tid = threadIdx.x, lane = tid & 63;
    const int wv = tid >> 6, wm = wv & 1, wn = wv >> 1;
    const int n31 = lane & 31, hi = lane >> 5;

    floatx16 acc[4][3];
    #pragma unroll
    for (int i = 0; i < 4; ++i)
        #pragma unroll
        for (int j = 0; j < 3; ++j) acc[i][j] = (floatx16)0.f;

    const int laneA = n31 * 72 + hi * 8;

    for (int kd = 0; kd < 5; ++kd) {
        const int dp = d + kd - 2;
        if (dp < 0 || dp >= 32) continue;            // WG-uniform
        // ---- stage d-slice into LDS (zero halos) ----
        const u16* srcbase = xt + (size_t)((b * 32 + dp) * 32) * 2304;
        for (int idx = tid; idx < 12 * 328; idx += 256) {
            int r = idx / 328, c = idx - r * 328;
            int hp = h0 + r - 2;
            uint4 val = make_uint4(0u, 0u, 0u, 0u);
            if (hp >= 0 && hp < 32 && c >= 18 && c < 306)
                val = *(const uint4*)(srcbase + (size_t)hp * 2304 + (c * 8 - 144));
            *(uint4*)(&sx[r * LP + c * 8]) = val;
        }
        __syncthreads();

        for (int kh = 0; kh < 5; ++kh) {
            const u16* bq = wt + ((size_t)((kd * 5 + kh) * 23 * 6) + wn * 3) * 512 + lane * 8;
            const u16* ar = &sx[(wm * 4 + kh) * LP + laneA];
            for (int ks = 0; ks < 23; ++ks) {
                short8 A0 = *(const short8*)(ar + ks * 16);
                short8 A1 = *(const short8*)(ar + ks * 16 + LP);
                short8 A2 = *(const short8*)(ar + ks * 16 + 2 * LP);
                short8 A3 = *(const short8*)(ar + ks * 16 + 3 * LP);
                short8 B0 = *(const short8*)(bq + (size_t)(ks * 6 + 0) * 512);
                short8 B1 = *(const short8*)(bq + (size_t)(ks * 6 + 1) * 512);
                short8 B2 = *(const short8*)(bq + (size_t)(ks * 6 + 2) * 512);
                acc[0][0] = __builtin_amdgcn_mfma_f32_32x32x16_bf16(A0, B0, acc[0][0], 0, 0, 0);
                acc[1][0] = __builtin_amdgcn_mfma_f32_32x32x16_bf16(A1, B0, acc[1][0], 0, 0, 0);
                acc[2][0] = __builtin_amdgcn_mfma_f32_32x32x16_bf16(A2, B0, acc[2][0], 0, 0, 0);
                acc[3][0] = __builtin_amdgcn_mfma_f32_32x32x16_bf16(A3, B0, acc[3][0], 0, 0, 0);
                acc[0][1] = __builtin_amdgcn_mfma_f32_32x32x16_bf16(A0, B1, acc[0][1], 0, 0, 0);
                acc[1][1] = __builtin_amdgcn_mfma_f32_32x32x16_bf16(A1, B1, acc[1][1], 0, 0, 0);
                acc[2][1] = __builtin_amdgcn_mfma_f32_32x32x16_bf16(A2, B1, acc[2][1], 0, 0, 0);
                acc[3][1] = __builtin_amdgcn_mfma_f32_32x32x16_bf16(A3, B1, acc[3][1], 0, 0, 0);
                acc[0][2] = __builtin_amdgcn_mfma_f32_32x32x16_bf16(A0, B2, acc[0][2], 0, 0, 0);
                acc[1][2] = __builtin_amdgcn_mfma_f32_32x32x16_bf16(A1, B2, acc[1][2], 0, 0, 0);
                acc[2][2] = __builtin_amdgcn_mfma_f32_32x32x16_bf16(A2, B2, acc[2][2], 0, 0, 0);
                acc[3][2] = __builtin_amdgcn_mfma_f32_32x32x16_bf16(A3, B2, acc[3][2], 0, 0, 0);
            }
        }
        __syncthreads();
    }

    // ---- epilogue: gate exchange via LDS (sx dead), then gated bf16 stores ----
    // C/D: n(co) = lane&31, m(w) = (reg&3) + 8*(reg>>2) + 4*(lane>>5).
    float* gl = (float*)sx;   // gl[pos 256][mul 32] f32 = 32 KB
    if (wn == 1) {
        #pragma unroll
        for (int mi = 0; mi < 4; ++mi) {
            const int posb = (wm * 4 + mi) * 32;
            #pragma unroll
            for (int r = 0; r < 16; ++r) {
                const int m = (r & 3) + 8 * (r >> 2) + 4 * hi;
                if (n31 >= 16) {   // block nb=4, co 144..159 -> mul 0..15
                    const float y = acc[mi][1][r] + gate_bias[n31 - 16];
                    gl[(posb + m) * 32 + (n31 - 16)] = 1.f / (1.f + __expf(-y));
                } else {           // block nb=5, co 160..175 -> mul 16..31
                    const float y = acc[mi][2][r] + gate_bias[16 + n31];
                    gl[(posb + m) * 32 + 16 + n31] = 1.f / (1.f + __expf(-y));
                }
            }
        }
    }
    __syncthreads();

    const int cobase = wn * 96;
    #pragma unroll
    for (int nj = 0; nj < 3; ++nj) {
        const int co = cobase + nj * 32 + n31;
        if (co >= 144) continue;   // gate channels / pad: not stored
        const bool is_scalar = (co < 16);
        const int mul = is_scalar ? 0 : ((co < 64) ? (co - 16) / 3 : 16 + (co - 64) / 5);
        const float sbv = is_scalar ? scalar_bias[co & 15] : 0.f;
        const float gbv = 0.f;
        (void)gbv;
        #pragma unroll
        for (int mi = 0; mi < 4; ++mi) {
            const int hrow = wm * 4 + mi;
            const size_t zrow = (size_t)((b * 32 + d) * 32 + h0 + hrow) * 32;
            #pragma unroll
            for (int r = 0; r < 16; ++r) {
                const int w = (r & 3) + 8 * (r >> 2) + 4 * hi;
                const float v = acc[mi][nj][r];
                float o;
                if (is_scalar) o = fmaxf(v + sbv, 0.f);
                else           o = v * gl[(hrow * 32 + w) * 32 + mul];
                zt[(zrow + w) * 144 + co] = f2bf(o);
            }
        }
    }
}

// ---------------------------------------------------------------------------
// Low-pass, separable 3-pass (coalesced).
// ---------------------------------------------------------------------------
__constant__ float LW5[5] = {0.03208210f, 0.23705644f, 0.46172277f, 0.23705644f, 0.03208210f};

__global__ __launch_bounds__(256) void k_lp_w(const u16* __restrict__ zt,
                                              u16* __restrict__ t1) {
    __shared__ u16 row[4608];
    const int bx = blockIdx.x;               // (b*32+d)*32+h, 4096 blocks
    const int tid = threadIdx.x;
    const uint4* src = (const uint4*)(zt + (size_t)bx * 4608);
    for (int i = tid; i < 576; i += 256) ((uint4*)row)[i] = src[i];
    __syncthreads();
    u16* dst = t1 + (size_t)bx * 2304;
    for (int e = tid; e < 2304; e += 256) {
        const int ow = e / 144, c = e - ow * 144;
        const int wb = 2 * ow - 2;
        float a = 0.f;
        #pragma unroll
        for (int kw = 0; kw < 5; ++kw) {
            const int wz = wb + kw;
            if (wz >= 0 && wz < 32) a += LW5[kw] * bf2f(row[wz * 144 + c]);
        }
        dst[e] = f2bf(a);
    }
}

__global__ __launch_bounds__(256) void k_lp_h(const u16* __restrict__ t1,
                                              u16* __restrict__ t2) {
    const int gid = blockIdx.x * 256 + threadIdx.x;  // 2304 blocks -> 589824 = 128*16*16*18
    const int c8 = gid % 18;
    int t = gid / 18;
    const int ow = t & 15; t >>= 4;
    const int oh = t & 15; t >>= 4;                  // t = b*32+d  (0..127)
    const u16* base = t1 + (size_t)t * 32 * 2304 + ow * 144 + c8 * 8;
    float a[8];
    #pragma unroll
    for (int j = 0; j < 8; ++j) a[j] = 0.f;
    const int hb = 2 * oh - 2;
    #pragma unroll
    for (int kh = 0; kh < 5; ++kh) {
        const int hz = hb + kh;
        if (hz < 0 || hz >= 32) continue;
        u16 v[8] __attribute__((aligned(16)));
        *(uint4*)v = *(const uint4*)(base + (size_t)hz * 2304);
        const float wgt = LW5[kh];
        #pragma unroll
        for (int j = 0; j < 8; ++j) a[j] += wgt * bf2f(v[j]);
    }
    u16 o[8] __attribute__((aligned(16)));
    #pragma unroll
    for (int j = 0; j < 8; ++j) o[j] = f2bf(a[j]);
    *(uint4*)(t2 + ((size_t)(t * 16 + oh) * 16 + ow) * 144 + c8 * 8) = *(const uint4*)o;
}

__global__ __launch_bounds__(256) void k_lp_d(const u16* __restrict__ t2,
                                              float* __restrict__ out) {
    __shared__ u16 rows[5 * 2304];
    const int bx = blockIdx.x;               // (b*16+od)*16+oh, 1024 blocks
    const int tid = threadIdx.x;
    const int oh = bx & 15, od = (bx >> 4) & 15, b = bx >> 8;
    const int db = 2 * od - 2;
    for (int i = tid; i < 5 * 288; i += 256) {
        const int kd = i / 288, j = i - kd * 288;
        const int dz = db + kd;
        uint4 v = make_uint4(0u, 0u, 0u, 0u);
        if (dz >= 0 && dz < 32)
            v = ((const uint4*)(t2 + ((size_t)((b * 32 + dz) * 16 + oh) * 16) * 144))[j];
        ((uint4*)rows)[i] = v;
    }
    __syncthreads();
    for (int e = tid; e < 2304; e += 256) {
        const int c = e >> 4, ow = e & 15;
        float a = 0.f;
        #pragma unroll
        for (int kd = 0; kd < 5; ++kd)
            a += LW5[kd] * bf2f(rows[kd * 2304 + ow * 144 + c]);
        out[(((size_t)b * 144 + c) << 12) + (od << 8) + (oh << 4) + ow] = a;
    }
}

// ---------------------------------------------------------------------------
extern "C" void kernel_launch(void* const* d_in, const int* in_sizes, int n_in,
                              void* d_out, int out_size, void* d_ws, size_t ws_size,
                              hipStream_t stream) {
    const float* x  = (const float*)d_in[0];   // 4*72*32^3
    const float* W  = (const float*)d_in[1];   // 176*72*125
    const float* sb = (const float*)d_in[2];   // 16
    const float* gb = (const float*)d_in[3];   // 32
    float* out = (float*)d_out;                // 4*144*16^3 f32

    char* ws = (char*)d_ws;
    u16* xt = (u16*)(ws);                      // 18,874,368 B  (dead after k_conv)
    u16* wt = (u16*)(ws + 18874368);           //  3,532,800 B
    u16* zt = (u16*)(ws + 22407168);           // 37,748,736 B  (dead after k_lp_w)
    u16* t1 = xt;                              // reuse
    u16* t2 = zt;                              // reuse

    hipLaunchKernelGGL(k_transpose_x, dim3(4096), dim3(256), 0, stream, x, xt);
    hipLaunchKernelGGL(k_prep_w,      dim3(863),  dim3(256), 0, stream, W, wt);
    hipLaunchKernelGGL(k_conv,        dim3(512),  dim3(256), 0, stream, xt, wt, sb, gb, zt);
    hipLaunchKernelGGL(k_lp_w,        dim3(4096), dim3(256), 0, stream, zt, t1);
    hipLaunchKernelGGL(k_lp_h,        dim3(2304), dim3(256), 0, stream, t1, t2);
    hipLaunchKernelGGL(k_lp_d,        dim3(1024), dim3(256), 0, stream, t2, out);
}

// Round 6
// 1248.219 us; speedup vs baseline: 1.4800x; 1.4800x over previous
//
#include <hip/hip_runtime.h>
#include <cstdint>
#include <cstddef>

typedef short short8 __attribute__((ext_vector_type(8)));
typedef float floatx16 __attribute__((ext_vector_type(16)));
typedef unsigned short u16;

__device__ __forceinline__ u16 f2bf(float f) {
    unsigned u = __float_as_uint(f);
    u += 0x7FFFu + ((u >> 16) & 1u);
    return (u16)(u >> 16);
}
__device__ __forceinline__ float bf2f(u16 h) {
    return __uint_as_float(((unsigned)h) << 16);
}

// ---------------------------------------------------------------------------
// Kernel 1: x [4][72][32][32][32] f32 (NCDHW)  ->  xt [4][32][32][32][72] bf16
// ---------------------------------------------------------------------------
__global__ __launch_bounds__(256) void k_transpose_x(const float* __restrict__ x,
                                                     u16* __restrict__ xt) {
    __shared__ float tile[72 * 33];
    const int bx = blockIdx.x;               // ((b*32+d)*32+h)
    const int tid = threadIdx.x;
    const int b = bx >> 10, d = (bx >> 5) & 31, h = bx & 31;
    const float* src = x + (size_t)b * 72 * 32768 + d * 1024 + h * 32;
    for (int e = tid; e < 2304; e += 256) {
        int ci = e >> 5, w = e & 31;
        tile[ci * 33 + w] = src[(size_t)ci * 32768 + w];
    }
    __syncthreads();
    u16* dst = xt + (size_t)bx * 2304;
    for (int e = tid; e < 2304; e += 256) {
        int w = e / 72, ci = e - w * 72;
        dst[e] = f2bf(tile[ci * 33 + w]);
    }
}

// ---------------------------------------------------------------------------
// Kernel 2: W [176][72][5][5][5] f32 -> wt bf16, 32x32x16 B-fragment layout:
//   wt[kd][kh][ks(23)][nb(6)][lane(64)][8]
//   co = nb*32 + (lane&31); k = ks*16 + (lane>>5)*8 + j  (k = kw*72+ci)
//   zero-pad k>=360 and co>=176.
// ---------------------------------------------------------------------------
__global__ __launch_bounds__(256) void k_prep_w(const float* __restrict__ W,
                                                u16* __restrict__ wt) {
    const int gid = blockIdx.x * 256 + threadIdx.x;   // 3450 frags * 64 = 220800
    if (gid >= 220800) return;
    const int frag = gid >> 6, lane = gid & 63;
    const int nb = frag % 6;
    int t = frag / 6;
    const int ks = t % 23;
    t = t / 23;
    const int kh = t % 5, kd = t / 5;
    const int n = lane & 31, q8 = (lane >> 5) * 8;
    const int co = nb * 32 + n;
    u16 v[8] __attribute__((aligned(16)));
    #pragma unroll
    for (int j = 0; j < 8; ++j) {
        int k = ks * 16 + q8 + j;
        u16 r = 0;
        if (k < 360 && co < 176) {
            int kw = k / 72, ci = k - kw * 72;
            r = f2bf(W[((size_t)co * 72 + ci) * 125 + kd * 25 + kh * 5 + kw]);
        }
        v[j] = r;
    }
    *(uint4*)(wt + (size_t)gid * 8) = *(const uint4*)v;
}

// ---------------------------------------------------------------------------
// Kernel 3: implicit-GEMM conv (32x32x16 MFMA) + fused gating.
// Grid 512 = (b:4, d:32, ht:4). WG 256 thr = 4 waves = 2 M-waves x 2 N-waves.
// Wave tile: mB=4 M-blocks (4 h-rows x 32 w) x nB=3 N-blocks (96 co).
// acc = 192 regs -> MUST live in AGPRs: launch_bounds(256,1) gives the
// 256V+256A per-wave budget (the (256,2) budget split 128V+128A and spilled
// acc to scratch in R4/R5 -> GBs of FETCH/WRITE).
// ---------------------------------------------------------------------------
#define LP 2624

__global__ __launch_bounds__(256, 1) void k_conv(const u16* __restrict__ xt,
                                                 const u16* __restrict__ wt,
                                                 const float* __restrict__ scalar_bias,
                                                 const float* __restrict__ gate_bias,
                                                 u16* __restrict__ zt) {
    __shared__ __align__(16) u16 sx[12 * LP];
    const int bx = blockIdx.x;
    const int ht = bx & 3, d = (bx >> 2) & 31, b = bx >> 7;
    const int h0 = ht * 8;
    const int tid = threadIdx.x, lane = tid & 63;
    const int wv = tid >> 6, wm = wv & 1, wn = wv >> 1;
    const int n31 = lane & 31, hi = lane >> 5;

    floatx16 acc[4][3];
    #pragma unroll
    for (int i = 0; i < 4; ++i)
        #pragma unroll
        for (int j = 0; j < 3; ++j) acc[i][j] = (floatx16)0.f;

    const int laneA = n31 * 72 + hi * 8;

    for (int kd = 0; kd < 5; ++kd) {
        const int dp = d + kd - 2;
        if (dp < 0 || dp >= 32) continue;            // WG-uniform
        // ---- stage d-slice into LDS (zero halos) ----
        const u16* srcbase = xt + (size_t)((b * 32 + dp) * 32) * 2304;
        for (int idx = tid; idx < 12 * 328; idx += 256) {
            int r = idx / 328, c = idx - r * 328;
            int hp = h0 + r - 2;
            uint4 val = make_uint4(0u, 0u, 0u, 0u);
            if (hp >= 0 && hp < 32 && c >= 18 && c < 306)
                val = *(const uint4*)(srcbase + (size_t)hp * 2304 + (c * 8 - 144));
            *(uint4*)(&sx[r * LP + c * 8]) = val;
        }
        __syncthreads();

        for (int kh = 0; kh < 5; ++kh) {
            const u16* bq = wt + ((size_t)((kd * 5 + kh) * 23 * 6) + wn * 3) * 512 + lane * 8;
            const u16* ar = &sx[(wm * 4 + kh) * LP + laneA];
            for (int ks = 0; ks < 23; ++ks) {
                short8 A0 = *(const short8*)(ar + ks * 16);
                short8 A1 = *(const short8*)(ar + ks * 16 + LP);
                short8 A2 = *(const short8*)(ar + ks * 16 + 2 * LP);
                short8 A3 = *(const short8*)(ar + ks * 16 + 3 * LP);
                short8 B0 = *(const short8*)(bq + (size_t)(ks * 6 + 0) * 512);
                short8 B1 = *(const short8*)(bq + (size_t)(ks * 6 + 1) * 512);
                short8 B2 = *(const short8*)(bq + (size_t)(ks * 6 + 2) * 512);
                acc[0][0] = __builtin_amdgcn_mfma_f32_32x32x16_bf16(A0, B0, acc[0][0], 0, 0, 0);
                acc[1][0] = __builtin_amdgcn_mfma_f32_32x32x16_bf16(A1, B0, acc[1][0], 0, 0, 0);
                acc[2][0] = __builtin_amdgcn_mfma_f32_32x32x16_bf16(A2, B0, acc[2][0], 0, 0, 0);
                acc[3][0] = __builtin_amdgcn_mfma_f32_32x32x16_bf16(A3, B0, acc[3][0], 0, 0, 0);
                acc[0][1] = __builtin_amdgcn_mfma_f32_32x32x16_bf16(A0, B1, acc[0][1], 0, 0, 0);
                acc[1][1] = __builtin_amdgcn_mfma_f32_32x32x16_bf16(A1, B1, acc[1][1], 0, 0, 0);
                acc[2][1] = __builtin_amdgcn_mfma_f32_32x32x16_bf16(A2, B1, acc[2][1], 0, 0, 0);
                acc[3][1] = __builtin_amdgcn_mfma_f32_32x32x16_bf16(A3, B1, acc[3][1], 0, 0, 0);
                acc[0][2] = __builtin_amdgcn_mfma_f32_32x32x16_bf16(A0, B2, acc[0][2], 0, 0, 0);
                acc[1][2] = __builtin_amdgcn_mfma_f32_32x32x16_bf16(A1, B2, acc[1][2], 0, 0, 0);
                acc[2][2] = __builtin_amdgcn_mfma_f32_32x32x16_bf16(A2, B2, acc[2][2], 0, 0, 0);
                acc[3][2] = __builtin_amdgcn_mfma_f32_32x32x16_bf16(A3, B2, acc[3][2], 0, 0, 0);
            }
        }
        __syncthreads();
    }

    // ---- epilogue: gate exchange via LDS (sx dead), then gated bf16 stores ----
    // C/D: n(co) = lane&31, m(w) = (reg&3) + 8*(reg>>2) + 4*(lane>>5).
    float* gl = (float*)sx;   // gl[pos 256][mul 32] f32 = 32 KB
    if (wn == 1) {
        #pragma unroll
        for (int mi = 0; mi < 4; ++mi) {
            const int posb = (wm * 4 + mi) * 32;
            #pragma unroll
            for (int r = 0; r < 16; ++r) {
                const int m = (r & 3) + 8 * (r >> 2) + 4 * hi;
                if (n31 >= 16) {   // block nb=4, co 144..159 -> mul 0..15
                    const float y = acc[mi][1][r] + gate_bias[n31 - 16];
                    gl[(posb + m) * 32 + (n31 - 16)] = 1.f / (1.f + __expf(-y));
                } else {           // block nb=5, co 160..175 -> mul 16..31
                    const float y = acc[mi][2][r] + gate_bias[16 + n31];
                    gl[(posb + m) * 32 + 16 + n31] = 1.f / (1.f + __expf(-y));
                }
            }
        }
    }
    __syncthreads();

    const int cobase = wn * 96;
    #pragma unroll
    for (int nj = 0; nj < 3; ++nj) {
        const int co = cobase + nj * 32 + n31;
        if (co >= 144) continue;   // gate channels / pad: not stored
        const bool is_scalar = (co < 16);
        const int mul = is_scalar ? 0 : ((co < 64) ? (co - 16) / 3 : 16 + (co - 64) / 5);
        const float sbv = is_scalar ? scalar_bias[co & 15] : 0.f;
        #pragma unroll
        for (int mi = 0; mi < 4; ++mi) {
            const int hrow = wm * 4 + mi;
            const size_t zrow = (size_t)((b * 32 + d) * 32 + h0 + hrow) * 32;
            #pragma unroll
            for (int r = 0; r < 16; ++r) {
                const int w = (r & 3) + 8 * (r >> 2) + 4 * hi;
                const float v = acc[mi][nj][r];
                float o;
                if (is_scalar) o = fmaxf(v + sbv, 0.f);
                else           o = v * gl[(hrow * 32 + w) * 32 + mul];
                zt[(zrow + w) * 144 + co] = f2bf(o);
            }
        }
    }
}

// ---------------------------------------------------------------------------
// Low-pass, separable 3-pass (coalesced).
// ---------------------------------------------------------------------------
__constant__ float LW5[5] = {0.03208210f, 0.23705644f, 0.46172277f, 0.23705644f, 0.03208210f};

__global__ __launch_bounds__(256) void k_lp_w(const u16* __restrict__ zt,
                                              u16* __restrict__ t1) {
    __shared__ u16 row[4608];
    const int bx = blockIdx.x;               // (b*32+d)*32+h, 4096 blocks
    const int tid = threadIdx.x;
    const uint4* src = (const uint4*)(zt + (size_t)bx * 4608);
    for (int i = tid; i < 576; i += 256) ((uint4*)row)[i] = src[i];
    __syncthreads();
    u16* dst = t1 + (size_t)bx * 2304;
    for (int e = tid; e < 2304; e += 256) {
        const int ow = e / 144, c = e - ow * 144;
        const int wb = 2 * ow - 2;
        float a = 0.f;
        #pragma unroll
        for (int kw = 0; kw < 5; ++kw) {
            const int wz = wb + kw;
            if (wz >= 0 && wz < 32) a += LW5[kw] * bf2f(row[wz * 144 + c]);
        }
        dst[e] = f2bf(a);
    }
}

__global__ __launch_bounds__(256) void k_lp_h(const u16* __restrict__ t1,
                                              u16* __restrict__ t2) {
    const int gid = blockIdx.x * 256 + threadIdx.x;  // 2304 blocks -> 589824 = 128*16*16*18
    const int c8 = gid % 18;
    int t = gid / 18;
    const int ow = t & 15; t >>= 4;
    const int oh = t & 15; t >>= 4;                  // t = b*32+d  (0..127)
    const u16* base = t1 + (size_t)t * 32 * 2304 + ow * 144 + c8 * 8;
    float a[8];
    #pragma unroll
    for (int j = 0; j < 8; ++j) a[j] = 0.f;
    const int hb = 2 * oh - 2;
    #pragma unroll
    for (int kh = 0; kh < 5; ++kh) {
        const int hz = hb + kh;
        if (hz < 0 || hz >= 32) continue;
        u16 v[8] __attribute__((aligned(16)));
        *(uint4*)v = *(const uint4*)(base + (size_t)hz * 2304);
        const float wgt = LW5[kh];
        #pragma unroll
        for (int j = 0; j < 8; ++j) a[j] += wgt * bf2f(v[j]);
    }
    u16 o[8] __attribute__((aligned(16)));
    #pragma unroll
    for (int j = 0; j < 8; ++j) o[j] = f2bf(a[j]);
    *(uint4*)(t2 + ((size_t)(t * 16 + oh) * 16 + ow) * 144 + c8 * 8) = *(const uint4*)o;
}

__global__ __launch_bounds__(256) void k_lp_d(const u16* __restrict__ t2,
                                              float* __restrict__ out) {
    __shared__ u16 rows[5 * 2304];
    const int bx = blockIdx.x;               // (b*16+od)*16+oh, 1024 blocks
    const int tid = threadIdx.x;
    const int oh = bx & 15, od = (bx >> 4) & 15, b = bx >> 8;
    const int db = 2 * od - 2;
    for (int i = tid; i < 5 * 288; i += 256) {
        const int kd = i / 288, j = i - kd * 288;
        const int dz = db + kd;
        uint4 v = make_uint4(0u, 0u, 0u, 0u);
        if (dz >= 0 && dz < 32)
            v = ((const uint4*)(t2 + ((size_t)((b * 32 + dz) * 16 + oh) * 16) * 144))[j];
        ((uint4*)rows)[i] = v;
    }
    __syncthreads();
    for (int e = tid; e < 2304; e += 256) {
        const int c = e >> 4, ow = e & 15;
        float a = 0.f;
        #pragma unroll
        for (int kd = 0; kd < 5; ++kd)
            a += LW5[kd] * bf2f(rows[kd * 2304 + ow * 144 + c]);
        out[(((size_t)b * 144 + c) << 12) + (od << 8) + (oh << 4) + ow] = a;
    }
}

// ---------------------------------------------------------------------------
extern "C" void kernel_launch(void* const* d_in, const int* in_sizes, int n_in,
                              void* d_out, int out_size, void* d_ws, size_t ws_size,
                              hipStream_t stream) {
    const float* x  = (const float*)d_in[0];   // 4*72*32^3
    const float* W  = (const float*)d_in[1];   // 176*72*125
    const float* sb = (const float*)d_in[2];   // 16
    const float* gb = (const float*)d_in[3];   // 32
    float* out = (float*)d_out;                // 4*144*16^3 f32

    char* ws = (char*)d_ws;
    u16* xt = (u16*)(ws);                      // 18,874,368 B  (dead after k_conv)
    u16* wt = (u16*)(ws + 18874368);           //  3,532,800 B
    u16* zt = (u16*)(ws + 22407168);           // 37,748,736 B  (dead after k_lp_w)
    u16* t1 = xt;                              // reuse
    u16* t2 = zt;                              // reuse

    hipLaunchKernelGGL(k_transpose_x, dim3(4096), dim3(256), 0, stream, x, xt);
    hipLaunchKernelGGL(k_prep_w,      dim3(863),  dim3(256), 0, stream, W, wt);
    hipLaunchKernelGGL(k_conv,        dim3(512),  dim3(256), 0, stream, xt, wt, sb, gb, zt);
    hipLaunchKernelGGL(k_lp_w,        dim3(4096), dim3(256), 0, stream, zt, t1);
    hipLaunchKernelGGL(k_lp_h,        dim3(2304), dim3(256), 0, stream, t1, t2);
    hipLaunchKernelGGL(k_lp_d,        dim3(1024), dim3(256), 0, stream, t2, out);
}

// Round 7
// 678.976 us; speedup vs baseline: 2.7208x; 1.8384x over previous
//
#include <hip/hip_runtime.h>
#include <cstdint>
#include <cstddef>

typedef short short8 __attribute__((ext_vector_type(8)));
typedef float floatx16 __attribute__((ext_vector_type(16)));
typedef unsigned short u16;

__device__ __forceinline__ u16 f2bf(float f) {
    unsigned u = __float_as_uint(f);
    u += 0x7FFFu + ((u >> 16) & 1u);
    return (u16)(u >> 16);
}
__device__ __forceinline__ float bf2f(u16 h) {
    return __uint_as_float(((unsigned)h) << 16);
}

// ---------------------------------------------------------------------------
// Kernel 1: x [4][72][32][32][32] f32 (NCDHW)  ->  xt [4][32][32][32][72] bf16
// ---------------------------------------------------------------------------
__global__ __launch_bounds__(256) void k_transpose_x(const float* __restrict__ x,
                                                     u16* __restrict__ xt) {
    __shared__ float tile[72 * 33];
    const int bx = blockIdx.x;               // ((b*32+d)*32+h)
    const int tid = threadIdx.x;
    const int b = bx >> 10, d = (bx >> 5) & 31, h = bx & 31;
    const float* src = x + (size_t)b * 72 * 32768 + d * 1024 + h * 32;
    for (int e = tid; e < 2304; e += 256) {
        int ci = e >> 5, w = e & 31;
        tile[ci * 33 + w] = src[(size_t)ci * 32768 + w];
    }
    __syncthreads();
    u16* dst = xt + (size_t)bx * 2304;
    for (int e = tid; e < 2304; e += 256) {
        int w = e / 72, ci = e - w * 72;
        dst[e] = f2bf(tile[ci * 33 + w]);
    }
}

// ---------------------------------------------------------------------------
// Kernel 2: W [176][72][5][5][5] f32 -> wt bf16, 32x32x16 B-fragment layout:
//   wt[kd][kh][ks(23)][nb(6)][lane(64)][8]
//   co = nb*32 + (lane&31); k = ks*16 + (lane>>5)*8 + j  (k = kw*72+ci)
//   zero-pad k>=360 and co>=176.
// ---------------------------------------------------------------------------
__global__ __launch_bounds__(256) void k_prep_w(const float* __restrict__ W,
                                                u16* __restrict__ wt) {
    const int gid = blockIdx.x * 256 + threadIdx.x;   // 3450 frags * 64 = 220800
    if (gid >= 220800) return;
    const int frag = gid >> 6, lane = gid & 63;
    const int nb = frag % 6;
    int t = frag / 6;
    const int ks = t % 23;
    t = t / 23;
    const int kh = t % 5, kd = t / 5;
    const int n = lane & 31, q8 = (lane >> 5) * 8;
    const int co = nb * 32 + n;
    u16 v[8] __attribute__((aligned(16)));
    #pragma unroll
    for (int j = 0; j < 8; ++j) {
        int k = ks * 16 + q8 + j;
        u16 r = 0;
        if (k < 360 && co < 176) {
            int kw = k / 72, ci = k - kw * 72;
            r = f2bf(W[((size_t)co * 72 + ci) * 125 + kd * 25 + kh * 5 + kw]);
        }
        v[j] = r;
    }
    *(uint4*)(wt + (size_t)gid * 8) = *(const uint4*)v;
}

// ---------------------------------------------------------------------------
// Kernel 3: implicit-GEMM conv (32x32x16 MFMA) + fused gating.
// Grid 512 = (b:4, d:32, ht:4). WG 256 thr = 4 waves = 2 M-waves x 2 N-waves.
// Wave tile: mB=4 M-blocks (4 h-rows x 32 w) x nB=3 N-blocks (96 co).
// acc = 192 regs FORCED into AGPRs via inline-asm "+a" constraints: the
// intrinsic path filled v0..v255 and spilled to scratch instead of using
// a0..a255 (R5: 2.4 GB scratch writes; R6: 220 MB). R1 proved ~300 unified
// regs (124v+176a) runs at ~6.7 waves/CU.
// ---------------------------------------------------------------------------
#define LP 2624

#define MFMA(accv, av, bv) \
    asm("v_mfma_f32_32x32x16_bf16 %0, %1, %2, %0" : "+a"(accv) : "v"(av), "v"(bv))

__global__ __launch_bounds__(256, 1) void k_conv(const u16* __restrict__ xt,
                                                 const u16* __restrict__ wt,
                                                 const float* __restrict__ scalar_bias,
                                                 const float* __restrict__ gate_bias,
                                                 u16* __restrict__ zt) {
    __shared__ __align__(16) u16 sx[12 * LP];
    const int bx = blockIdx.x;
    const int ht = bx & 3, d = (bx >> 2) & 31, b = bx >> 7;
    const int h0 = ht * 8;
    const int tid = threadIdx.x, lane = tid & 63;
    const int wv = tid >> 6, wm = wv & 1, wn = wv >> 1;
    const int n31 = lane & 31, hi = lane >> 5;

    floatx16 acc[4][3];
    #pragma unroll
    for (int i = 0; i < 4; ++i)
        #pragma unroll
        for (int j = 0; j < 3; ++j) acc[i][j] = (floatx16)0.f;
    asm volatile("s_nop 3");   // accvgpr_write -> MFMA srcC hazard guard

    const int laneA = n31 * 72 + hi * 8;

    for (int kd = 0; kd < 5; ++kd) {
        const int dp = d + kd - 2;
        if (dp < 0 || dp >= 32) continue;            // WG-uniform
        // ---- stage d-slice into LDS (zero halos) ----
        const u16* srcbase = xt + (size_t)((b * 32 + dp) * 32) * 2304;
        for (int idx = tid; idx < 12 * 328; idx += 256) {
            int r = idx / 328, c = idx - r * 328;
            int hp = h0 + r - 2;
            uint4 val = make_uint4(0u, 0u, 0u, 0u);
            if (hp >= 0 && hp < 32 && c >= 18 && c < 306)
                val = *(const uint4*)(srcbase + (size_t)hp * 2304 + (c * 8 - 144));
            *(uint4*)(&sx[r * LP + c * 8]) = val;
        }
        __syncthreads();

        for (int kh = 0; kh < 5; ++kh) {
            const u16* bq = wt + ((size_t)((kd * 5 + kh) * 23 * 6) + wn * 3) * 512 + lane * 8;
            const u16* ar = &sx[(wm * 4 + kh) * LP + laneA];
            for (int ks = 0; ks < 23; ++ks) {
                short8 A0 = *(const short8*)(ar + ks * 16);
                short8 A1 = *(const short8*)(ar + ks * 16 + LP);
                short8 A2 = *(const short8*)(ar + ks * 16 + 2 * LP);
                short8 A3 = *(const short8*)(ar + ks * 16 + 3 * LP);
                short8 B0 = *(const short8*)(bq + (size_t)(ks * 6 + 0) * 512);
                short8 B1 = *(const short8*)(bq + (size_t)(ks * 6 + 1) * 512);
                short8 B2 = *(const short8*)(bq + (size_t)(ks * 6 + 2) * 512);
                MFMA(acc[0][0], A0, B0);
                MFMA(acc[1][0], A1, B0);
                MFMA(acc[2][0], A2, B0);
                MFMA(acc[3][0], A3, B0);
                MFMA(acc[0][1], A0, B1);
                MFMA(acc[1][1], A1, B1);
                MFMA(acc[2][1], A2, B1);
                MFMA(acc[3][1], A3, B1);
                MFMA(acc[0][2], A0, B2);
                MFMA(acc[1][2], A1, B2);
                MFMA(acc[2][2], A2, B2);
                MFMA(acc[3][2], A3, B2);
            }
        }
        __syncthreads();
    }

    // MFMA -> accvgpr_read hazard guard (compiler can't see through asm)
    asm volatile("s_nop 7\n\ts_nop 7\n\ts_nop 7");

    // ---- epilogue: gate exchange via LDS (sx dead), then gated bf16 stores ----
    // C/D: n(co) = lane&31, m(w) = (reg&3) + 8*(reg>>2) + 4*(lane>>5).
    float* gl = (float*)sx;   // gl[pos 256][mul 32] f32 = 32 KB
    if (wn == 1) {
        #pragma unroll
        for (int mi = 0; mi < 4; ++mi) {
            const int posb = (wm * 4 + mi) * 32;
            #pragma unroll
            for (int r = 0; r < 16; ++r) {
                const int m = (r & 3) + 8 * (r >> 2) + 4 * hi;
                if (n31 >= 16) {   // block nb=4, co 144..159 -> mul 0..15
                    const float y = acc[mi][1][r] + gate_bias[n31 - 16];
                    gl[(posb + m) * 32 + (n31 - 16)] = 1.f / (1.f + __expf(-y));
                } else {           // block nb=5, co 160..175 -> mul 16..31
                    const float y = acc[mi][2][r] + gate_bias[16 + n31];
                    gl[(posb + m) * 32 + 16 + n31] = 1.f / (1.f + __expf(-y));
                }
            }
        }
    }
    __syncthreads();

    const int cobase = wn * 96;
    #pragma unroll
    for (int nj = 0; nj < 3; ++nj) {
        const int co = cobase + nj * 32 + n31;
        if (co >= 144) continue;   // gate channels / pad: not stored
        const bool is_scalar = (co < 16);
        const int mul = is_scalar ? 0 : ((co < 64) ? (co - 16) / 3 : 16 + (co - 64) / 5);
        const float sbv = is_scalar ? scalar_bias[co & 15] : 0.f;
        #pragma unroll
        for (int mi = 0; mi < 4; ++mi) {
            const int hrow = wm * 4 + mi;
            const size_t zrow = (size_t)((b * 32 + d) * 32 + h0 + hrow) * 32;
            #pragma unroll
            for (int r = 0; r < 16; ++r) {
                const int w = (r & 3) + 8 * (r >> 2) + 4 * hi;
                const float v = acc[mi][nj][r];
                float o;
                if (is_scalar) o = fmaxf(v + sbv, 0.f);
                else           o = v * gl[(hrow * 32 + w) * 32 + mul];
                zt[(zrow + w) * 144 + co] = f2bf(o);
            }
        }
    }
}

// ---------------------------------------------------------------------------
// Low-pass, separable 3-pass (coalesced).
// ---------------------------------------------------------------------------
__constant__ float LW5[5] = {0.03208210f, 0.23705644f, 0.46172277f, 0.23705644f, 0.03208210f};

__global__ __launch_bounds__(256) void k_lp_w(const u16* __restrict__ zt,
                                              u16* __restrict__ t1) {
    __shared__ u16 row[4608];
    const int bx = blockIdx.x;               // (b*32+d)*32+h, 4096 blocks
    const int tid = threadIdx.x;
    const uint4* src = (const uint4*)(zt + (size_t)bx * 4608);
    for (int i = tid; i < 576; i += 256) ((uint4*)row)[i] = src[i];
    __syncthreads();
    u16* dst = t1 + (size_t)bx * 2304;
    for (int e = tid; e < 2304; e += 256) {
        const int ow = e / 144, c = e - ow * 144;
        const int wb = 2 * ow - 2;
        float a = 0.f;
        #pragma unroll
        for (int kw = 0; kw < 5; ++kw) {
            const int wz = wb + kw;
            if (wz >= 0 && wz < 32) a += LW5[kw] * bf2f(row[wz * 144 + c]);
        }
        dst[e] = f2bf(a);
    }
}

__global__ __launch_bounds__(256) void k_lp_h(const u16* __restrict__ t1,
                                              u16* __restrict__ t2) {
    const int gid = blockIdx.x * 256 + threadIdx.x;  // 2304 blocks -> 589824 = 128*16*16*18
    const int c8 = gid % 18;
    int t = gid / 18;
    const int ow = t & 15; t >>= 4;
    const int oh = t & 15; t >>= 4;                  // t = b*32+d  (0..127)
    const u16* base = t1 + (size_t)t * 32 * 2304 + ow * 144 + c8 * 8;
    float a[8];
    #pragma unroll
    for (int j = 0; j < 8; ++j) a[j] = 0.f;
    const int hb = 2 * oh - 2;
    #pragma unroll
    for (int kh = 0; kh < 5; ++kh) {
        const int hz = hb + kh;
        if (hz < 0 || hz >= 32) continue;
        u16 v[8] __attribute__((aligned(16)));
        *(uint4*)v = *(const uint4*)(base + (size_t)hz * 2304);
        const float wgt = LW5[kh];
        #pragma unroll
        for (int j = 0; j < 8; ++j) a[j] += wgt * bf2f(v[j]);
    }
    u16 o[8] __attribute__((aligned(16)));
    #pragma unroll
    for (int j = 0; j < 8; ++j) o[j] = f2bf(a[j]);
    *(uint4*)(t2 + ((size_t)(t * 16 + oh) * 16 + ow) * 144 + c8 * 8) = *(const uint4*)o;
}

__global__ __launch_bounds__(256) void k_lp_d(const u16* __restrict__ t2,
                                              float* __restrict__ out) {
    __shared__ u16 rows[5 * 2304];
    const int bx = blockIdx.x;               // (b*16+od)*16+oh, 1024 blocks
    const int tid = threadIdx.x;
    const int oh = bx & 15, od = (bx >> 4) & 15, b = bx >> 8;
    const int db = 2 * od - 2;
    for (int i = tid; i < 5 * 288; i += 256) {
        const int kd = i / 288, j = i - kd * 288;
        const int dz = db + kd;
        uint4 v = make_uint4(0u, 0u, 0u, 0u);
        if (dz >= 0 && dz < 32)
            v = ((const uint4*)(t2 + ((size_t)((b * 32 + dz) * 16 + oh) * 16) * 144))[j];
        ((uint4*)rows)[i] = v;
    }
    __syncthreads();
    for (int e = tid; e < 2304; e += 256) {
        const int c = e >> 4, ow = e & 15;
        float a = 0.f;
        #pragma unroll
        for (int kd = 0; kd < 5; ++kd)
            a += LW5[kd] * bf2f(rows[kd * 2304 + ow * 144 + c]);
        out[(((size_t)b * 144 + c) << 12) + (od << 8) + (oh << 4) + ow] = a;
    }
}

// ---------------------------------------------------------------------------
extern "C" void kernel_launch(void* const* d_in, const int* in_sizes, int n_in,
                              void* d_out, int out_size, void* d_ws, size_t ws_size,
                              hipStream_t stream) {
    const float* x  = (const float*)d_in[0];   // 4*72*32^3
    const float* W  = (const float*)d_in[1];   // 176*72*125
    const float* sb = (const float*)d_in[2];   // 16
    const float* gb = (const float*)d_in[3];   // 32
    float* out = (float*)d_out;                // 4*144*16^3 f32

    char* ws = (char*)d_ws;
    u16* xt = (u16*)(ws);                      // 18,874,368 B  (dead after k_conv)
    u16* wt = (u16*)(ws + 18874368);           //  3,532,800 B
    u16* zt = (u16*)(ws + 22407168);           // 37,748,736 B  (dead after k_lp_w)
    u16* t1 = xt;                              // reuse
    u16* t2 = zt;                              // reuse

    hipLaunchKernelGGL(k_transpose_x, dim3(4096), dim3(256), 0, stream, x, xt);
    hipLaunchKernelGGL(k_prep_w,      dim3(863),  dim3(256), 0, stream, W, wt);
    hipLaunchKernelGGL(k_conv,        dim3(512),  dim3(256), 0, stream, xt, wt, sb, gb, zt);
    hipLaunchKernelGGL(k_lp_w,        dim3(4096), dim3(256), 0, stream, zt, t1);
    hipLaunchKernelGGL(k_lp_h,        dim3(2304), dim3(256), 0, stream, t1, t2);
    hipLaunchKernelGGL(k_lp_d,        dim3(1024), dim3(256), 0, stream, t2, out);
}